// Round 11
// baseline (75.305 us; speedup 1.0000x reference)
//
#include <hip/hip_runtime.h>

#define NIMG 8
#define NC 19
#define HW (512*1024)
#define BPI 128          // blocks per image
#define TPB 256
#define ITERS 2          // 8 px/thread/iter: HW/(BPI*TPB*8) = 2
#define PXB  (HW/BPI)    // pixels per block per plane = 4096 (16KB)
#define OLD_CL 11
#define NWAVE (TPB/64)

typedef float    f32x2 __attribute__((ext_vector_type(2)));
typedef float    f32x4 __attribute__((ext_vector_type(4)));
typedef unsigned u32x2 __attribute__((ext_vector_type(2)));

// ---------------- main pass: per-pixel softmax^2 per-class sums + argmax hist ----------------
// Row-burst loading: per plane per iter, TWO adjacent dwordx4 (4KB-apart halves of an
// 8KB contiguous block window) issued back-to-back -> same-DRAM-row request clustering.
// Partials written TRANSPOSED: sPart[c][n][bl], hPart[c][n][bl]
__global__ __launch_bounds__(TPB, 2) void iw_main(const float* __restrict__ in,
                                                  float* __restrict__ sPart,
                                                  unsigned* __restrict__ hPart) {
    const int b   = blockIdx.x;        // 0 .. NIMG*BPI-1
    const int n   = b >> 7;            // image (BPI=128)
    const int bl  = b & (BPI - 1);
    const int tid = threadIdx.x;
    const float* img = in + (size_t)n * NC * HW + (size_t)bl * PXB;

    float    acc[NC];
    unsigned hc[5];                    // 19 counters x 8-bit fields (16 px/thread)
#pragma unroll
    for (int c = 0; c < NC; ++c) acc[c] = 0.f;
#pragma unroll
    for (int r = 0; r < 5; ++r) hc[r] = 0u;

    const float L2E = 1.4426950408889634f;

    for (int it = 0; it < ITERS; ++it) {
        // block window for this iter: 8KB/plane = [it*2048, it*2048+2048) floats
        const int q = it * (TPB * 8) + tid * 4;      // first x4; second at +1024 floats

        f32x4 xa[NC], xb[NC];
#pragma unroll
        for (int c = 0; c < NC; ++c) {
            const float* gp = img + (size_t)c * HW + q;
            xa[c] = *reinterpret_cast<const f32x4*>(gp);          // adjacent pair:
            xb[c] = *reinterpret_cast<const f32x4*>(gp + 1024);   // same 8KB window
        }

#define PIXEL(V, K)                                                           \
        {                                                                     \
            float m = V[0][K];                                                \
            _Pragma("unroll")                                                 \
            for (int c = 1; c < NC; ++c) m = fmaxf(m, V[c][K]);               \
            int mi = NC - 1;                                                  \
            _Pragma("unroll")                                                 \
            for (int c = NC - 2; c >= 0; --c) mi = (V[c][K] == m) ? c : mi;   \
            {                                                                 \
                const unsigned inc = 1u << ((mi & 3) * 8);                    \
                const int r = mi >> 2;                                        \
                hc[0] += (r == 0) ? inc : 0u;                                 \
                hc[1] += (r == 1) ? inc : 0u;                                 \
                hc[2] += (r == 2) ? inc : 0u;                                 \
                hc[3] += (r == 3) ? inc : 0u;                                 \
                hc[4] += (r == 4) ? inc : 0u;                                 \
            }                                                                 \
            const float ml = m * L2E;                                         \
            float e[NC]; float d = 0.f;                                       \
            _Pragma("unroll")                                                 \
            for (int c = 0; c < NC; ++c) {                                    \
                e[c] = exp2f(fmaf(V[c][K], L2E, -ml));                        \
                d += e[c];                                                    \
            }                                                                 \
            const float inv  = __builtin_amdgcn_rcpf(d);                      \
            const float inv2 = inv * inv;                                     \
            _Pragma("unroll")                                                 \
            for (int c = 0; c < NC; ++c)                                      \
                acc[c] = fmaf(e[c] * e[c], inv2, acc[c]);                     \
        }

        PIXEL(xa, 0); PIXEL(xa, 1); PIXEL(xa, 2); PIXEL(xa, 3);
        PIXEL(xb, 0); PIXEL(xb, 1); PIXEL(xb, 2); PIXEL(xb, 3);
#undef PIXEL
    }

    // ---- unpack hist, wave (64-lane) butterfly reduce ----
    unsigned hu[NC];
#pragma unroll
    for (int c = 0; c < NC; ++c) hu[c] = (hc[c >> 2] >> ((c & 3) * 8)) & 0xFFu;

#pragma unroll
    for (int c = 0; c < NC; ++c) {
#pragma unroll
        for (int off = 32; off >= 1; off >>= 1) {
            acc[c] += __shfl_xor(acc[c], off, 64);
            hu[c]  += (unsigned)__shfl_xor((int)hu[c], off, 64);
        }
    }

    // ---- cross-wave combine via LDS, deterministic ----
    __shared__ float    ls[NWAVE][NC];
    __shared__ unsigned lh[NWAVE][NC];
    const int wave = tid >> 6;
    const int lane = tid & 63;
    if (lane == 0) {
#pragma unroll
        for (int c = 0; c < NC; ++c) { ls[wave][c] = acc[c]; lh[wave][c] = hu[c]; }
    }
    __syncthreads();
    if (tid < NC) {
        float s = 0.f; unsigned h = 0u;
#pragma unroll
        for (int w = 0; w < NWAVE; ++w) { s += ls[w][tid]; h += lh[w][tid]; }
        // transposed: [c][n][bl]
        sPart[(size_t)tid * (NIMG * BPI) + n * BPI + bl] = s;
        hPart[(size_t)tid * (NIMG * BPI) + n * BPI + bl] = h;
    }
}

// ---------------- final reduce: coalesced wave-parallel partial reduce -> weight -> loss ----------------
__global__ __launch_bounds__(1024) void iw_final(const float* __restrict__ sPart,
                                                 const unsigned* __restrict__ hPart,
                                                 float* __restrict__ out) {
    __shared__ float    sRed[NIMG * NC];
    __shared__ unsigned hRed[NIMG * NC];
    __shared__ double contrib[NIMG * NC];
    __shared__ double histL[NIMG * NC];
    __shared__ double hsum[NIMG];

    const int t    = threadIdx.x;
    const int wv   = t >> 6;           // 16 waves
    const int lane = t & 63;

    // each wave handles pairs wv, wv+16, ... (10 slots cover 152 pairs); BPI=128 -> f32x2/lane
#pragma unroll
    for (int i = 0; i < 10; ++i) {
        const int pair = wv + 16 * i;
        if (pair < NIMG * NC) {
            const size_t base = (size_t)pair * BPI + lane * 2;
            const f32x2 sv = *reinterpret_cast<const f32x2*>(sPart + base);
            const u32x2 hv = *reinterpret_cast<const u32x2*>(hPart + base);
            float    s = sv[0] + sv[1];
            unsigned h = hv[0] + hv[1];
#pragma unroll
            for (int off = 32; off >= 1; off >>= 1) {
                s += __shfl_xor(s, off, 64);
                h += (unsigned)__shfl_xor((int)h, off, 64);
            }
            if (lane == 0) { sRed[pair] = s; hRed[pair] = h; }
        }
    }
    __syncthreads();

    // pair index is [c][n] linear; convert to canonical (n,c)
    if (t < NIMG * NC) {
        const int c = t / NIMG, n = t % NIMG;
        const int idx = n * NC + c;
        const unsigned h = hRed[t];
        histL[idx]   = (h == 0u) ? 1.0 : (double)h;
        contrib[idx] = (double)sRed[t];              // temporarily S
    }
    __syncthreads();
    if (t < NIMG) {
        double hs = 0.0;
        for (int c = 0; c < NC; ++c) hs += histL[t * NC + c];
        hsum[t] = hs;
    }
    __syncthreads();
    if (t < NIMG * NC) {
        const int n = t / NC, c = t % NC;
        const double w = (c < OLD_CL) ? 1.0 : pow(hsum[n] / histL[t], 0.2);
        contrib[t] = w * contrib[t];
    }
    __syncthreads();
    if (t == 0) {
        double tot = 0.0;
        for (int i = 0; i < NIMG * NC; ++i) tot += contrib[i];
        out[0] = (float)(-tot / (double)((size_t)NIMG * NC * HW));
    }
}

extern "C" void kernel_launch(void* const* d_in, const int* in_sizes, int n_in,
                              void* d_out, int out_size, void* d_ws, size_t ws_size,
                              hipStream_t stream) {
    const float* in = (const float*)d_in[0];
    float* out = (float*)d_out;

    float*    sPart = (float*)d_ws;
    unsigned* hPart = (unsigned*)((char*)d_ws + (size_t)NC * NIMG * BPI * sizeof(float));

    iw_main<<<dim3(NIMG * BPI), TPB, 0, stream>>>(in, sPart, hPart);
    iw_final<<<1, 1024, 0, stream>>>(sPart, hPart, out);
}

// Round 12
// 68.292 us; speedup vs baseline: 1.1027x; 1.1027x over previous
//
#include <hip/hip_runtime.h>

#define NIMG 8
#define NC 19
#define HW (512*1024)
#define BPI 128          // blocks per image
#define TPB 256
#define ITERS 8          // float2 chunks/thread: (HW/2)/(BPI*TPB) = 262144/32768
#define CPB (ITERS*TPB)  // float2 chunks per block = 2048 (16KB/plane contiguous)
#define OLD_CL 11
#define NWAVE (TPB/64)

typedef float    f32x2 __attribute__((ext_vector_type(2)));
typedef unsigned u32x2 __attribute__((ext_vector_type(2)));

// ---------------- main pass: per-pixel softmax^2 per-class sums + argmax hist ----------------
// Best-known config (R4/R10): f32x2 loads, contiguous 16KB/plane block windows,
// 4 waves/SIMD, packed 8-bit hist, transposed partials [c][n][bl].
__global__ __launch_bounds__(TPB, 4) void iw_main(const float* __restrict__ in,
                                                  float* __restrict__ sPart,
                                                  unsigned* __restrict__ hPart) {
    const int b   = blockIdx.x;        // 0 .. NIMG*BPI-1
    const int n   = b >> 7;            // image (BPI=128)
    const int bl  = b & (BPI - 1);
    const int tid = threadIdx.x;
    const float* img = in + (size_t)n * NC * HW;

    float    acc[NC];
    unsigned hc[5];                    // 19 counters x 8-bit fields (max 16 px/thread)
#pragma unroll
    for (int c = 0; c < NC; ++c) acc[c] = 0.f;
#pragma unroll
    for (int r = 0; r < 5; ++r) hc[r] = 0u;

    const float L2E = 1.4426950408889634f;

    for (int it = 0; it < ITERS; ++it) {
        // contiguous per-block mapping: block streams 16KB/plane sequentially
        const int    chunk = bl * CPB + it * TPB + tid;
        const size_t p     = (size_t)chunk * 2;

        float x0[NC], x1[NC];
#pragma unroll
        for (int c = 0; c < NC; ++c) {
            const f32x2 t = __builtin_nontemporal_load(
                reinterpret_cast<const f32x2*>(img + (size_t)c * HW + p));
            x0[c] = t[0]; x1[c] = t[1];
        }

#define PIXEL(X)                                                              \
        {                                                                     \
            float m = X[0];                                                   \
            _Pragma("unroll")                                                 \
            for (int c = 1; c < NC; ++c) m = fmaxf(m, X[c]);                  \
            int mi = NC - 1;                                                  \
            _Pragma("unroll")                                                 \
            for (int c = NC - 2; c >= 0; --c) mi = (X[c] == m) ? c : mi;      \
            {                                                                 \
                const unsigned inc = 1u << ((mi & 3) * 8);                    \
                const int r = mi >> 2;                                        \
                hc[0] += (r == 0) ? inc : 0u;                                 \
                hc[1] += (r == 1) ? inc : 0u;                                 \
                hc[2] += (r == 2) ? inc : 0u;                                 \
                hc[3] += (r == 3) ? inc : 0u;                                 \
                hc[4] += (r == 4) ? inc : 0u;                                 \
            }                                                                 \
            const float ml = m * L2E;                                         \
            float e[NC]; float d = 0.f;                                       \
            _Pragma("unroll")                                                 \
            for (int c = 0; c < NC; ++c) {                                    \
                e[c] = exp2f(fmaf(X[c], L2E, -ml));                           \
                d += e[c];                                                    \
            }                                                                 \
            const float inv  = __builtin_amdgcn_rcpf(d);                      \
            const float inv2 = inv * inv;                                     \
            _Pragma("unroll")                                                 \
            for (int c = 0; c < NC; ++c)                                      \
                acc[c] = fmaf(e[c] * e[c], inv2, acc[c]);                     \
        }

        PIXEL(x0); PIXEL(x1);
#undef PIXEL
    }

    // ---- unpack hist, wave (64-lane) butterfly reduce ----
    unsigned hu[NC];
#pragma unroll
    for (int c = 0; c < NC; ++c) hu[c] = (hc[c >> 2] >> ((c & 3) * 8)) & 0xFFu;

#pragma unroll
    for (int c = 0; c < NC; ++c) {
#pragma unroll
        for (int off = 32; off >= 1; off >>= 1) {
            acc[c] += __shfl_xor(acc[c], off, 64);
            hu[c]  += (unsigned)__shfl_xor((int)hu[c], off, 64);
        }
    }

    // ---- cross-wave combine via LDS (4 waves/block), deterministic ----
    __shared__ float    ls[NWAVE][NC];
    __shared__ unsigned lh[NWAVE][NC];
    const int wave = tid >> 6;
    const int lane = tid & 63;
    if (lane == 0) {
#pragma unroll
        for (int c = 0; c < NC; ++c) { ls[wave][c] = acc[c]; lh[wave][c] = hu[c]; }
    }
    __syncthreads();
    if (tid < NC) {
        float s = 0.f; unsigned h = 0u;
#pragma unroll
        for (int w = 0; w < NWAVE; ++w) { s += ls[w][tid]; h += lh[w][tid]; }
        // transposed: [c][n][bl]
        sPart[(size_t)tid * (NIMG * BPI) + n * BPI + bl] = s;
        hPart[(size_t)tid * (NIMG * BPI) + n * BPI + bl] = h;
    }
}

// ---------------- final reduce: coalesced wave-parallel partial reduce -> weight -> loss ----------------
__global__ __launch_bounds__(1024) void iw_final(const float* __restrict__ sPart,
                                                 const unsigned* __restrict__ hPart,
                                                 float* __restrict__ out) {
    __shared__ float    sRed[NIMG * NC];
    __shared__ unsigned hRed[NIMG * NC];
    __shared__ double contrib[NIMG * NC];
    __shared__ double histL[NIMG * NC];
    __shared__ double hsum[NIMG];

    const int t    = threadIdx.x;
    const int wv   = t >> 6;           // 16 waves
    const int lane = t & 63;

    // each wave handles pairs wv, wv+16, ... (10 slots cover 152 pairs); BPI=128 -> f32x2/lane
#pragma unroll
    for (int i = 0; i < 10; ++i) {
        const int pair = wv + 16 * i;
        if (pair < NIMG * NC) {
            const size_t base = (size_t)pair * BPI + lane * 2;
            const f32x2 sv = *reinterpret_cast<const f32x2*>(sPart + base);
            const u32x2 hv = *reinterpret_cast<const u32x2*>(hPart + base);
            float    s = sv[0] + sv[1];
            unsigned h = hv[0] + hv[1];
#pragma unroll
            for (int off = 32; off >= 1; off >>= 1) {
                s += __shfl_xor(s, off, 64);
                h += (unsigned)__shfl_xor((int)h, off, 64);
            }
            if (lane == 0) { sRed[pair] = s; hRed[pair] = h; }
        }
    }
    __syncthreads();

    // pair index is [c][n] linear; convert to canonical (n,c)
    if (t < NIMG * NC) {
        const int c = t / NIMG, n = t % NIMG;
        const int idx = n * NC + c;
        const unsigned h = hRed[t];
        histL[idx]   = (h == 0u) ? 1.0 : (double)h;
        contrib[idx] = (double)sRed[t];              // temporarily S
    }
    __syncthreads();
    if (t < NIMG) {
        double hs = 0.0;
        for (int c = 0; c < NC; ++c) hs += histL[t * NC + c];
        hsum[t] = hs;
    }
    __syncthreads();
    if (t < NIMG * NC) {
        const int n = t / NC, c = t % NC;
        const double w = (c < OLD_CL) ? 1.0 : pow(hsum[n] / histL[t], 0.2);
        contrib[t] = w * contrib[t];
    }
    __syncthreads();
    if (t == 0) {
        double tot = 0.0;
        for (int i = 0; i < NIMG * NC; ++i) tot += contrib[i];
        out[0] = (float)(-tot / (double)((size_t)NIMG * NC * HW));
    }
}

extern "C" void kernel_launch(void* const* d_in, const int* in_sizes, int n_in,
                              void* d_out, int out_size, void* d_ws, size_t ws_size,
                              hipStream_t stream) {
    const float* in = (const float*)d_in[0];
    float* out = (float*)d_out;

    float*    sPart = (float*)d_ws;
    unsigned* hPart = (unsigned*)((char*)d_ws + (size_t)NC * NIMG * BPI * sizeof(float));

    iw_main<<<dim3(NIMG * BPI), TPB, 0, stream>>>(in, sPart, hPart);
    iw_final<<<1, 1024, 0, stream>>>(sPart, hPart, out);
}